// Round 3
// baseline (758.175 us; speedup 1.0000x reference)
//
#include <hip/hip_runtime.h>
#include <hip/hip_bf16.h>

#define S_SEQ 8192
#define D_DIM 1024
#define NCLS 7

typedef __bf16 bf16x8 __attribute__((ext_vector_type(8)));
typedef float f32x4 __attribute__((ext_vector_type(4)));

typedef const __attribute__((address_space(1))) void* gas_ptr;
typedef __attribute__((address_space(3))) void* las_ptr;
#define GLL(gp, lp) __builtin_amdgcn_global_load_lds((gas_ptr)(const void*)(gp), (las_ptr)(void*)(lp), 16, 0, 0)

__device__ __forceinline__ unsigned short f2bf(float f) {
    unsigned int u = __builtin_bit_cast(unsigned int, f);
    u = (u + 0x7FFFu + ((u >> 16) & 1u)) >> 16;
    return (unsigned short)u;
}

// ---------------- elementwise fp32 -> bf16 ----------------
__global__ __launch_bounds__(256) void k_f32_to_bf16(const float* __restrict__ src,
                                                     unsigned short* __restrict__ dst, int n4) {
    int i = blockIdx.x * 256 + threadIdx.x;
    if (i >= n4) return;
    float4 v = ((const float4*)src)[i];
    ushort4 o;
    o.x = f2bf(v.x); o.y = f2bf(v.y); o.z = f2bf(v.z); o.w = f2bf(v.w);
    ((ushort4*)dst)[i] = o;
}

// ---------------- sum of two fp32 arrays -> bf16 ----------------
__global__ __launch_bounds__(256) void k_sum2_bf16(const float* __restrict__ a,
                                                   const float* __restrict__ b,
                                                   unsigned short* __restrict__ dst, int n4) {
    int i = blockIdx.x * 256 + threadIdx.x;
    if (i >= n4) return;
    float4 va = ((const float4*)a)[i];
    float4 vb = ((const float4*)b)[i];
    ushort4 o;
    o.x = f2bf(va.x + vb.x); o.y = f2bf(va.y + vb.y);
    o.z = f2bf(va.z + vb.z); o.w = f2bf(va.w + vb.w);
    ((ushort4*)dst)[i] = o;
}

// ---------------- transpose fp32 [R][C] -> bf16 [C][R] ----------------
__global__ __launch_bounds__(256) void k_transpose_f32_bf16(const float* __restrict__ src,
                                                            unsigned short* __restrict__ dst,
                                                            int R, int C) {
    __shared__ unsigned short t[64][80];
    int r0 = blockIdx.x * 64, c0 = blockIdx.y * 64;
    int tid = threadIdx.x;
    int rr = tid >> 4, cc = (tid & 15) << 2;
#pragma unroll
    for (int p = 0; p < 4; ++p) {
        int r = rr + p * 16;
        float4 v = *(const float4*)(src + (size_t)(r0 + r) * C + c0 + cc);
        t[cc + 0][r] = f2bf(v.x);
        t[cc + 1][r] = f2bf(v.y);
        t[cc + 2][r] = f2bf(v.z);
        t[cc + 3][r] = f2bf(v.w);
    }
    __syncthreads();
    int wr = tid >> 3, wc = (tid & 7) << 3;
#pragma unroll
    for (int p = 0; p < 2; ++p) {
        int c = wr + p * 32;
        uint4 v8 = *(const uint4*)&t[c][wc];
        *(uint4*)(dst + (size_t)(c0 + c) * R + r0 + wc) = v8;
    }
}

// ---------------- transpose bf16 [R][C] -> bf16 [C][R] ----------------
__global__ __launch_bounds__(256) void k_transpose_bf16(const unsigned short* __restrict__ src,
                                                        unsigned short* __restrict__ dst,
                                                        int R, int C) {
    __shared__ unsigned short t[64][80];
    int r0 = blockIdx.x * 64, c0 = blockIdx.y * 64;
    int tid = threadIdx.x;
    int rr = tid >> 3, cc = (tid & 7) << 3;
#pragma unroll
    for (int p = 0; p < 2; ++p) {
        int r = rr + p * 32;
        uint4 v = *(const uint4*)(src + (size_t)(r0 + r) * C + c0 + cc);
        const unsigned short* pv = (const unsigned short*)&v;
#pragma unroll
        for (int i = 0; i < 8; ++i) t[cc + i][r] = pv[i];
    }
    __syncthreads();
    int wr = tid >> 3, wc = (tid & 7) << 3;
#pragma unroll
    for (int p = 0; p < 2; ++p) {
        int c = wr + p * 32;
        uint4 v8 = *(const uint4*)&t[c][wc];
        *(uint4*)(dst + (size_t)(c0 + c) * R + r0 + wc) = v8;
    }
}

// ---------------- LayerNorm row kernel (strided input): bf16 out ----------------
__global__ __launch_bounds__(256) void k_ln_bf16(const float* __restrict__ Y, int ldy,
                                                 const float* __restrict__ bias,
                                                 const float* __restrict__ g,
                                                 const float* __restrict__ beta,
                                                 unsigned short* __restrict__ out) {
    __shared__ float red[8];
    int row = blockIdx.x, tid = threadIdx.x;
    float4 y = *(const float4*)(Y + (size_t)row * ldy + tid * 4);
    float4 b4 = *(const float4*)(bias + tid * 4);
    y.x += b4.x; y.y += b4.y; y.z += b4.z; y.w += b4.w;
    float s = y.x + y.y + y.z + y.w;
    float s2 = y.x * y.x + y.y * y.y + y.z * y.z + y.w * y.w;
#pragma unroll
    for (int o = 32; o; o >>= 1) { s += __shfl_down(s, o); s2 += __shfl_down(s2, o); }
    int lane = tid & 63, wv = tid >> 6;
    if (lane == 0) { red[wv] = s; red[4 + wv] = s2; }
    __syncthreads();
    s = red[0] + red[1] + red[2] + red[3];
    s2 = red[4] + red[5] + red[6] + red[7];
    float m = s * (1.0f / D_DIM);
    float var = s2 * (1.0f / D_DIM) - m * m;
    float rs = rsqrtf(var + 1e-5f);
    float4 g4 = *(const float4*)(g + tid * 4);
    float4 be4 = *(const float4*)(beta + tid * 4);
    ushort4 o4;
    o4.x = f2bf((y.x - m) * rs * g4.x + be4.x);
    o4.y = f2bf((y.y - m) * rs * g4.y + be4.y);
    o4.z = f2bf((y.z - m) * rs * g4.z + be4.z);
    o4.w = f2bf((y.w - m) * rs * g4.w + be4.w);
    *(ushort4*)(out + (size_t)row * D_DIM + tid * 4) = o4;
}

// ---------------- combine per-tile stats: rmax, rrecip ----------------
__global__ __launch_bounds__(256) void k_stats_reduce(const float* __restrict__ pmax,
                                                      const float* __restrict__ psum,
                                                      float* __restrict__ rmax,
                                                      float* __restrict__ rrecip, int nblk) {
    int row = blockIdx.x * 4 + (threadIdx.x >> 6);
    int lane = threadIdx.x & 63;
    const float* pm = pmax + (size_t)row * nblk;
    const float* ps = psum + (size_t)row * nblk;
    float m = -3.4e38f;
    for (int j = lane; j < nblk; j += 64) m = fmaxf(m, pm[j]);
#pragma unroll
    for (int mk = 32; mk; mk >>= 1) m = fmaxf(m, __shfl_xor(m, mk));
    float s = 0.0f;
    for (int j = lane; j < nblk; j += 64) s += ps[j] * __expf(pm[j] - m);
#pragma unroll
    for (int mk = 32; mk; mk >>= 1) s += __shfl_xor(s, mk);
    if (lane == 0) { rmax[row] = m; rrecip[row] = 1.0f / s; }
}

// ---------------- normalize (in-place fp32) + transposed bf16 copy ----------------
__global__ __launch_bounds__(256) void k_norm_transpose(float* __restrict__ A,
                                                        const float* __restrict__ rmax,
                                                        const float* __restrict__ rrecip,
                                                        unsigned short* __restrict__ At) {
    __shared__ unsigned short t[64][80];
    int t0 = blockIdx.x * 64, s0 = blockIdx.y * 64;
    int tid = threadIdx.x;
    int rr = tid >> 4, cc = (tid & 15) << 2;
#pragma unroll
    for (int p = 0; p < 4; ++p) {
        int r = rr + p * 16;
        float m = rmax[t0 + r], rc = rrecip[t0 + r];
        size_t off = (size_t)(t0 + r) * S_SEQ + s0 + cc;
        float4 v = *(const float4*)(A + off);
        v.x = __expf(v.x - m) * rc;
        v.y = __expf(v.y - m) * rc;
        v.z = __expf(v.z - m) * rc;
        v.w = __expf(v.w - m) * rc;
        *(float4*)(A + off) = v;
        t[cc + 0][r] = f2bf(v.x);
        t[cc + 1][r] = f2bf(v.y);
        t[cc + 2][r] = f2bf(v.z);
        t[cc + 3][r] = f2bf(v.w);
    }
    __syncthreads();
    int wr = tid >> 3, wc = (tid & 7) << 3;
#pragma unroll
    for (int p = 0; p < 2; ++p) {
        int c = wr + p * 32;
        uint4 v8 = *(const uint4*)&t[c][wc];
        *(uint4*)(At + (size_t)(s0 + c) * S_SEQ + t0 + wc) = v8;
    }
}

// ---------------- classifier: c = x @ Wc + bc ----------------
__global__ __launch_bounds__(256) void k_classifier(const float* __restrict__ x,
                                                    const float* __restrict__ Wc,
                                                    const float* __restrict__ bc,
                                                    float* __restrict__ outc) {
    __shared__ float red[4][NCLS];
    int row = blockIdx.x, tid = threadIdx.x;
    float4 xv = *(const float4*)(x + (size_t)row * D_DIM + tid * 4);
    const float* w0 = Wc + (size_t)(tid * 4) * NCLS;
    float acc[NCLS];
#pragma unroll
    for (int j = 0; j < NCLS; ++j)
        acc[j] = xv.x * w0[j] + xv.y * w0[NCLS + j] + xv.z * w0[2 * NCLS + j] + xv.w * w0[3 * NCLS + j];
#pragma unroll
    for (int j = 0; j < NCLS; ++j)
#pragma unroll
        for (int o = 32; o; o >>= 1) acc[j] += __shfl_down(acc[j], o);
    int lane = tid & 63, wv = tid >> 6;
    if (lane == 0) {
#pragma unroll
        for (int j = 0; j < NCLS; ++j) red[wv][j] = acc[j];
    }
    __syncthreads();
    if (tid < NCLS) {
        float s = red[0][tid] + red[1][tid] + red[2][tid] + red[3][tid];
        outc[(size_t)row * NCLS + tid] = s + bc[tid];
    }
}

// ============ pipelined bf16 GEMM: C[M,N] = scale*A[M,K]*B[N,K]^T (+bias) ============
// BM=256, BK=32, 512 threads (8 waves), 4 LDS buffers, 3-tiles-ahead prefetch with
// counted vmcnt, LDS XOR swizzle via inverse-swizzled global source, setprio around
// MFMA, bijective XCD block swizzle with bm-fastest ordering (B-panel L2-resident).
// Optional split-K (SK in {1,2}: sk==0 -> C0, sk==1 -> C1) and optional fused
// softmax-stat epilogue (per-row max / sum-exp over each wave's 64-col tile).
template<int BN, int WM, int WN>
__global__ __launch_bounds__(512) void k_gemm_big(const unsigned short* __restrict__ A,
                                                  const unsigned short* __restrict__ B,
                                                  float* __restrict__ C0,
                                                  float* __restrict__ C1,
                                                  int M, int N, int K, int SK,
                                                  float scale,
                                                  const float* __restrict__ bias,
                                                  float* __restrict__ pmax,
                                                  float* __restrict__ psum) {
    constexpr int MREP = 256 / WM / 16;
    constexpr int NREP = BN / WN / 16;
    constexpr int PHASES = MREP / 4;
    constexpr int BISS = BN / 128;
    constexpr int TISS = 2 + BISS;
    constexpr int ASLOT = 256 * 32;
    constexpr int BSLOT = BN * 32;
    constexpr int SLOT = ASLOT + BSLOT;
    __shared__ unsigned short lds[4 * SLOT];

    const int tid = threadIdx.x;
    const int lane = tid & 63;
    const int wid = tid >> 6;
    const int wm = wid / WN;
    const int wn = wid % WN;
    const int fm = lane & 15;
    const int g = lane >> 4;

    // bijective XCD swizzle (grid % 8 == 0), bm-fastest decomposition
    const int nbm = M >> 8;
    const int nbn = N / BN;
    const int per = nbm * nbn;
    const int nwg = gridDim.x;
    int bid = blockIdx.x;
    int wg = ((nwg & 7) == 0) ? ((bid & 7) * (nwg >> 3) + (bid >> 3)) : bid;
    const int sk = wg / per;
    const int rem = wg % per;
    const int bn = rem / nbm;
    const int bm = rem % nbm;
    const int brow = bm << 8;
    const int bcol = bn * BN;

    const int Ksub = K / SK;
    const int NT = Ksub >> 5;
    float* __restrict__ C = (sk == 0) ? C0 : C1;

    // ----- staging (inverse-swizzled global source, linear LDS dest) -----
    const int arow = tid >> 2;
    const int scb = ((tid & 3) << 4) ^ ((arow & 6) << 3);
    const unsigned short* gA = A + (size_t)(brow + arow) * K + sk * Ksub + (scb >> 1);
    const unsigned short* gB = B + (size_t)(bcol + arow) * K + sk * Ksub + (scb >> 1);
    unsigned short* lA = lds + tid * 8;
    unsigned short* lB = lds + ASLOT + tid * 8;
    const size_t rows128 = (size_t)128 * K;

    auto stageA = [&](int kt, int slot) {
        const unsigned short* s = gA + ((size_t)kt << 5);
        unsigned short* d = lA + slot * SLOT;
        GLL(s, d);
        GLL(s + rows128, d + 4096);
    };
    auto stageB = [&](int kt, int slot) {
        const unsigned short* s = gB + ((size_t)kt << 5);
        unsigned short* d = lB + slot * SLOT;
#pragma unroll
        for (int h = 0; h < BISS; ++h)
            GLL(s + (size_t)h * rows128, d + h * 4096);
    };

    // ----- fragment read bases (swizzled) -----
    const int cbf = (((g << 4) ^ ((fm & 6) << 3)) >> 1);
    const unsigned short* fA = lds + (wm * (256 / WM) + fm) * 32 + cbf;
    const unsigned short* fB = lds + ASLOT + (wn * (BN / WN) + fm) * 32 + cbf;

    f32x4 acc[MREP][NREP] = {};

    stageA(0, 0); stageB(0, 0);
    stageA(1, 1); stageB(1, 1);
    stageA(2, 2); stageB(2, 2);
    asm volatile("s_waitcnt vmcnt(%0)" :: "n"(2 * TISS) : "memory");
    __builtin_amdgcn_s_barrier();

    for (int t = 0; t < NT; ++t) {
        const int slot = t & 3;
        const unsigned short* sA = fA + slot * SLOT;
        const unsigned short* sB = fB + slot * SLOT;
        const int pslot = (t + 3) & 3;
        const bool pf = (t + 3) < NT;

        bf16x8 bfr[NREP];
        bf16x8 afr[4];
#pragma unroll
        for (int i = 0; i < 4; ++i) afr[i] = *(const bf16x8*)(sA + i * 512);
#pragma unroll
        for (int j = 0; j < NREP; ++j) bfr[j] = *(const bf16x8*)(sB + j * 512);
        if (pf) {
            stageA(t + 3, pslot);
            if (PHASES == 1) stageB(t + 3, pslot);
        }
        __builtin_amdgcn_s_barrier();
        asm volatile("s_waitcnt lgkmcnt(0)" ::: "memory");
        __builtin_amdgcn_s_setprio(1);
#pragma unroll
        for (int i = 0; i < 4; ++i)
#pragma unroll
            for (int j = 0; j < NREP; ++j)
                acc[i][j] = __builtin_amdgcn_mfma_f32_16x16x32_bf16(afr[i], bfr[j], acc[i][j], 0, 0, 0);
        __builtin_amdgcn_s_setprio(0);
        __builtin_amdgcn_s_barrier();

        if (PHASES == 2) {
#pragma unroll
            for (int i = 0; i < 4; ++i) afr[i] = *(const bf16x8*)(sA + (i + 4) * 512);
            if (pf) stageB(t + 3, pslot);
            __builtin_amdgcn_s_barrier();
            asm volatile("s_waitcnt lgkmcnt(0)" ::: "memory");
            __builtin_amdgcn_s_setprio(1);
#pragma unroll
            for (int i = 0; i < 4; ++i)
#pragma unroll
                for (int j = 0; j < NREP; ++j)
                    acc[(i + 4) % MREP][j] = __builtin_amdgcn_mfma_f32_16x16x32_bf16(afr[i], bfr[j], acc[(i + 4) % MREP][j], 0, 0, 0);
            __builtin_amdgcn_s_setprio(0);
        }

        if (t + 1 < NT) {
            if (t + 3 < NT)
                asm volatile("s_waitcnt vmcnt(%0)" :: "n"(2 * TISS) : "memory");
            else if (t + 2 < NT)
                asm volatile("s_waitcnt vmcnt(%0)" :: "n"(TISS) : "memory");
            else
                asm volatile("s_waitcnt vmcnt(0)" ::: "memory");
        }
        __builtin_amdgcn_s_barrier();
    }

    // ---- fused softmax-stat epilogue (per-row max & sum-exp over 64 cols) ----
    if (psum) {
        const int nblk = N >> 6;
        const int cblk = (bcol >> 6) + wn;
#pragma unroll
        for (int i = 0; i < MREP; ++i) {
#pragma unroll
            for (int r = 0; r < 4; ++r) {
                float v0 = acc[i][0][r] * scale, v1 = acc[i][1][r] * scale;
                float v2 = acc[i][2][r] * scale, v3 = acc[i][3][r] * scale;
                float mv = fmaxf(fmaxf(v0, v1), fmaxf(v2, v3));
#pragma unroll
                for (int mk = 1; mk < 16; mk <<= 1) mv = fmaxf(mv, __shfl_xor(mv, mk));
                float sv = __expf(v0 - mv) + __expf(v1 - mv) + __expf(v2 - mv) + __expf(v3 - mv);
#pragma unroll
                for (int mk = 1; mk < 16; mk <<= 1) sv += __shfl_xor(sv, mk);
                if (fm == 0) {
                    int row = brow + wm * (256 / WM) + i * 16 + (g << 2) + r;
                    pmax[(size_t)row * nblk + cblk] = mv;
                    psum[(size_t)row * nblk + cblk] = sv;
                }
            }
        }
    }

    // ---- store ----
    const int r0 = g << 2;
#pragma unroll
    for (int i = 0; i < MREP; ++i) {
#pragma unroll
        for (int j = 0; j < NREP; ++j) {
            int col = bcol + wn * (BN / WN) + j * 16 + fm;
            float badd = bias ? bias[col] : 0.0f;
#pragma unroll
            for (int r = 0; r < 4; ++r) {
                int row = brow + wm * (256 / WM) + i * 16 + r0 + r;
                C[(size_t)row * N + col] = acc[i][j][r] * scale + badd;
            }
        }
    }
}

extern "C" void kernel_launch(void* const* d_in, const int* in_sizes, int n_in,
                              void* d_out, int out_size, void* d_ws, size_t ws_size,
                              hipStream_t stream) {
    const float* x     = (const float*)d_in[0];
    const float* Wq    = (const float*)d_in[1];
    const float* bq    = (const float*)d_in[2];
    const float* gq    = (const float*)d_in[3];
    const float* betaq = (const float*)d_in[4];
    const float* Wk    = (const float*)d_in[5];
    const float* bk    = (const float*)d_in[6];
    const float* gk    = (const float*)d_in[7];
    const float* betak = (const float*)d_in[8];
    const float* Wv    = (const float*)d_in[9];
    const float* bv    = (const float*)d_in[10];
    const float* gv    = (const float*)d_in[11];
    const float* betav = (const float*)d_in[12];
    const float* Wo    = (const float*)d_in[13];
    const float* bo    = (const float*)d_in[14];
    const float* Wc    = (const float*)d_in[15];
    const float* bc    = (const float*)d_in[16];

    float* out_o    = (float*)d_out;
    float* out_c    = out_o + (size_t)S_SEQ * D_DIM;
    float* out_attn = out_c + (size_t)S_SEQ * NCLS;

    char* cur = (char*)d_ws;
    auto alloc = [&](size_t bytes) {
        char* p = cur;
        cur += (bytes + 255) & ~(size_t)255;
        return p;
    };
    const size_t SD2 = (size_t)S_SEQ * D_DIM * 2;
    const size_t DD2 = (size_t)D_DIM * D_DIM * 2;
    unsigned short* xb   = (unsigned short*)alloc(SD2);
    unsigned short* wqkv = (unsigned short*)alloc(3 * DD2);
    unsigned short* wto  = (unsigned short*)alloc(DD2);
    unsigned short* qb   = (unsigned short*)alloc(SD2);
    unsigned short* kb   = (unsigned short*)alloc(SD2);
    unsigned short* vb   = (unsigned short*)alloc(SD2);
    unsigned short* Vt   = (unsigned short*)alloc(SD2);
    unsigned short* valb = (unsigned short*)alloc(SD2);
    float* rmax   = (float*)alloc((size_t)S_SEQ * 4);
    float* rrecip = (float*)alloc((size_t)S_SEQ * 4);
    unsigned short* At = (unsigned short*)alloc((size_t)S_SEQ * S_SEQ * 2);

    // overlays (dead-region reuse, zero ws growth):
    // pmax/psum (8192 x 128 fp32 each = 8.4 MB) over xb -- xb dead after QKV GEMM.
    float* pmax = (float*)xb;
    float* psum = pmax + (size_t)S_SEQ * 128;
    // split-K partial #1 (33.55 MB) over qb+kb -- dead after QK^T.
    float* part1 = (float*)qb;

    const int n4_xd = S_SEQ * D_DIM / 4;

    // x -> bf16
    k_f32_to_bf16<<<n4_xd / 256, 256, 0, stream>>>(x, xb, n4_xd);
    // weight transposes: fp32 [K][N] -> bf16 [N][K]; q/k/v concatenated along N
    k_transpose_f32_bf16<<<dim3(16, 16), 256, 0, stream>>>(Wq, wqkv, D_DIM, D_DIM);
    k_transpose_f32_bf16<<<dim3(16, 16), 256, 0, stream>>>(Wk, wqkv + (size_t)D_DIM * D_DIM, D_DIM, D_DIM);
    k_transpose_f32_bf16<<<dim3(16, 16), 256, 0, stream>>>(Wv, wqkv + (size_t)2 * D_DIM * D_DIM, D_DIM, D_DIM);
    k_transpose_f32_bf16<<<dim3(16, 16), 256, 0, stream>>>(Wo, wto, D_DIM, D_DIM);
    // classifier (independent)
    k_classifier<<<S_SEQ, 256, 0, stream>>>(x, Wc, bc, out_c);

    // fused QKV GEMM: [8192][3072] fp32 into out_attn scratch
    float* qkv = out_attn;
    k_gemm_big<128, 4, 2><<<(S_SEQ / 256) * (3 * D_DIM / 128), 512, 0, stream>>>(
        xb, wqkv, qkv, nullptr, S_SEQ, 3 * D_DIM, D_DIM, 1, 1.0f, nullptr, nullptr, nullptr);
    // per-chain LayerNorm -> bf16
    k_ln_bf16<<<S_SEQ, 256, 0, stream>>>(qkv,              3 * D_DIM, bq, gq, betaq, qb);
    k_ln_bf16<<<S_SEQ, 256, 0, stream>>>(qkv + D_DIM,      3 * D_DIM, bk, gk, betak, kb);
    k_ln_bf16<<<S_SEQ, 256, 0, stream>>>(qkv + 2 * D_DIM,  3 * D_DIM, bv, gv, betav, vb);

    // V^T for the A^T V GEMM
    k_transpose_bf16<<<dim3(S_SEQ / 64, D_DIM / 64), 256, 0, stream>>>(vb, Vt, S_SEQ, D_DIM);

    // logits = q k^T / 32 -> out_attn, with fused per-tile softmax stats
    k_gemm_big<256, 2, 4><<<(S_SEQ / 256) * (S_SEQ / 256), 512, 0, stream>>>(
        qb, kb, out_attn, nullptr, S_SEQ, S_SEQ, D_DIM, 1, 0.03125f, nullptr, pmax, psum);

    // combine stats, then normalize-in-place + transposed bf16 copy
    k_stats_reduce<<<S_SEQ / 4, 256, 0, stream>>>(pmax, psum, rmax, rrecip, S_SEQ / 64);
    k_norm_transpose<<<dim3(S_SEQ / 64, S_SEQ / 64), 256, 0, stream>>>(out_attn, rmax, rrecip, At);

    // values = A^T V: split-K=2 (sk0 -> out_o scratch, sk1 -> part1), then sum -> bf16
    k_gemm_big<256, 2, 4><<<2 * (S_SEQ / 256) * (D_DIM / 256), 512, 0, stream>>>(
        At, Vt, out_o, part1, S_SEQ, D_DIM, S_SEQ, 2, 1.0f, nullptr, nullptr, nullptr);
    k_sum2_bf16<<<n4_xd / 256, 256, 0, stream>>>(out_o, part1, valb, n4_xd);

    // o = values @ Wo + bo
    k_gemm_big<128, 4, 2><<<(S_SEQ / 256) * (D_DIM / 128), 512, 0, stream>>>(
        valb, wto, out_o, nullptr, S_SEQ, D_DIM, D_DIM, 1, 1.0f, bo, nullptr, nullptr);
}

// Round 4
// 660.669 us; speedup vs baseline: 1.1476x; 1.1476x over previous
//
#include <hip/hip_runtime.h>
#include <hip/hip_bf16.h>

#define S_SEQ 8192
#define D_DIM 1024
#define NCLS 7

typedef __bf16 bf16x8 __attribute__((ext_vector_type(8)));
typedef float f32x4 __attribute__((ext_vector_type(4)));

typedef const __attribute__((address_space(1))) void* gas_ptr;
typedef __attribute__((address_space(3))) void* las_ptr;
#define GLL(gp, lp) __builtin_amdgcn_global_load_lds((gas_ptr)(const void*)(gp), (las_ptr)(void*)(lp), 16, 0, 0)

__device__ __forceinline__ unsigned short f2bf(float f) {
    unsigned int u = __builtin_bit_cast(unsigned int, f);
    u = (u + 0x7FFFu + ((u >> 16) & 1u)) >> 16;
    return (unsigned short)u;
}
__device__ __forceinline__ float bf2f(unsigned short h) {
    unsigned int u = ((unsigned int)h) << 16;
    return __builtin_bit_cast(float, u);
}

// ---------------- elementwise fp32 -> bf16 ----------------
__global__ __launch_bounds__(256) void k_f32_to_bf16(const float* __restrict__ src,
                                                     unsigned short* __restrict__ dst, int n4) {
    int i = blockIdx.x * 256 + threadIdx.x;
    if (i >= n4) return;
    float4 v = ((const float4*)src)[i];
    ushort4 o;
    o.x = f2bf(v.x); o.y = f2bf(v.y); o.z = f2bf(v.z); o.w = f2bf(v.w);
    ((ushort4*)dst)[i] = o;
}

// ---------------- transpose fp32 [R][C] -> bf16 [C][R] ----------------
__global__ __launch_bounds__(256) void k_transpose_f32_bf16(const float* __restrict__ src,
                                                            unsigned short* __restrict__ dst,
                                                            int R, int C) {
    __shared__ unsigned short t[64][80];
    int r0 = blockIdx.x * 64, c0 = blockIdx.y * 64;
    int tid = threadIdx.x;
    int rr = tid >> 4, cc = (tid & 15) << 2;
#pragma unroll
    for (int p = 0; p < 4; ++p) {
        int r = rr + p * 16;
        float4 v = *(const float4*)(src + (size_t)(r0 + r) * C + c0 + cc);
        t[cc + 0][r] = f2bf(v.x);
        t[cc + 1][r] = f2bf(v.y);
        t[cc + 2][r] = f2bf(v.z);
        t[cc + 3][r] = f2bf(v.w);
    }
    __syncthreads();
    int wr = tid >> 3, wc = (tid & 7) << 3;
#pragma unroll
    for (int p = 0; p < 2; ++p) {
        int c = wr + p * 32;
        uint4 v8 = *(const uint4*)&t[c][wc];
        *(uint4*)(dst + (size_t)(c0 + c) * R + r0 + wc) = v8;
    }
}

// ---------------- transpose bf16 [R][C] -> bf16 [C][R] ----------------
__global__ __launch_bounds__(256) void k_transpose_bf16(const unsigned short* __restrict__ src,
                                                        unsigned short* __restrict__ dst,
                                                        int R, int C) {
    __shared__ unsigned short t[64][80];
    int r0 = blockIdx.x * 64, c0 = blockIdx.y * 64;
    int tid = threadIdx.x;
    int rr = tid >> 3, cc = (tid & 7) << 3;
#pragma unroll
    for (int p = 0; p < 2; ++p) {
        int r = rr + p * 32;
        uint4 v = *(const uint4*)(src + (size_t)(r0 + r) * C + c0 + cc);
        const unsigned short* pv = (const unsigned short*)&v;
#pragma unroll
        for (int i = 0; i < 8; ++i) t[cc + i][r] = pv[i];
    }
    __syncthreads();
    int wr = tid >> 3, wc = (tid & 7) << 3;
#pragma unroll
    for (int p = 0; p < 2; ++p) {
        int c = wr + p * 32;
        uint4 v8 = *(const uint4*)&t[c][wc];
        *(uint4*)(dst + (size_t)(c0 + c) * R + r0 + wc) = v8;
    }
}

// ---------------- LayerNorm row kernel (strided input): bf16 out ----------------
__global__ __launch_bounds__(256) void k_ln_bf16(const float* __restrict__ Y, int ldy,
                                                 const float* __restrict__ bias,
                                                 const float* __restrict__ g,
                                                 const float* __restrict__ beta,
                                                 unsigned short* __restrict__ out) {
    __shared__ float red[8];
    int row = blockIdx.x, tid = threadIdx.x;
    float4 y = *(const float4*)(Y + (size_t)row * ldy + tid * 4);
    float4 b4 = *(const float4*)(bias + tid * 4);
    y.x += b4.x; y.y += b4.y; y.z += b4.z; y.w += b4.w;
    float s = y.x + y.y + y.z + y.w;
    float s2 = y.x * y.x + y.y * y.y + y.z * y.z + y.w * y.w;
#pragma unroll
    for (int o = 32; o; o >>= 1) { s += __shfl_down(s, o); s2 += __shfl_down(s2, o); }
    int lane = tid & 63, wv = tid >> 6;
    if (lane == 0) { red[wv] = s; red[4 + wv] = s2; }
    __syncthreads();
    s = red[0] + red[1] + red[2] + red[3];
    s2 = red[4] + red[5] + red[6] + red[7];
    float m = s * (1.0f / D_DIM);
    float var = s2 * (1.0f / D_DIM) - m * m;
    float rs = rsqrtf(var + 1e-5f);
    float4 g4 = *(const float4*)(g + tid * 4);
    float4 be4 = *(const float4*)(beta + tid * 4);
    ushort4 o4;
    o4.x = f2bf((y.x - m) * rs * g4.x + be4.x);
    o4.y = f2bf((y.y - m) * rs * g4.y + be4.y);
    o4.z = f2bf((y.z - m) * rs * g4.z + be4.z);
    o4.w = f2bf((y.w - m) * rs * g4.w + be4.w);
    *(ushort4*)(out + (size_t)row * D_DIM + tid * 4) = o4;
}

// ---------------- combine per-tile stats: rmax, rrecip ----------------
__global__ __launch_bounds__(256) void k_stats_reduce(const float* __restrict__ pmax,
                                                      const float* __restrict__ psum,
                                                      float* __restrict__ rmax,
                                                      float* __restrict__ rrecip, int nblk) {
    int row = blockIdx.x * 4 + (threadIdx.x >> 6);
    int lane = threadIdx.x & 63;
    const float* pm = pmax + (size_t)row * nblk;
    const float* ps = psum + (size_t)row * nblk;
    float m = -3.4e38f;
    for (int j = lane; j < nblk; j += 64) m = fmaxf(m, pm[j]);
#pragma unroll
    for (int mk = 32; mk; mk >>= 1) m = fmaxf(m, __shfl_xor(m, mk));
    float s = 0.0f;
    for (int j = lane; j < nblk; j += 64) s += ps[j] * __expf(pm[j] - m);
#pragma unroll
    for (int mk = 32; mk; mk >>= 1) s += __shfl_xor(s, mk);
    if (lane == 0) { rmax[row] = m; rrecip[row] = 1.0f / s; }
}

// ------- normalize: src (bf16 logits or fp32 logits) -> fp32 attn + bf16 At -------
template<int BF16SRC>
__global__ __launch_bounds__(256) void k_norm_transpose(const unsigned short* __restrict__ src16,
                                                        const float* __restrict__ src32,
                                                        float* __restrict__ attn,
                                                        const float* __restrict__ rmax,
                                                        const float* __restrict__ rrecip,
                                                        unsigned short* __restrict__ At) {
    __shared__ unsigned short t[64][80];
    int t0 = blockIdx.x * 64, s0 = blockIdx.y * 64;
    int tid = threadIdx.x;
    int rr = tid >> 4, cc = (tid & 15) << 2;
#pragma unroll
    for (int p = 0; p < 4; ++p) {
        int r = rr + p * 16;
        float m = rmax[t0 + r], rc = rrecip[t0 + r];
        size_t off = (size_t)(t0 + r) * S_SEQ + s0 + cc;
        float4 v;
        if (BF16SRC) {
            ushort4 u = *(const ushort4*)(src16 + off);
            v.x = bf2f(u.x); v.y = bf2f(u.y); v.z = bf2f(u.z); v.w = bf2f(u.w);
        } else {
            v = *(const float4*)(src32 + off);
        }
        v.x = __expf(v.x - m) * rc;
        v.y = __expf(v.y - m) * rc;
        v.z = __expf(v.z - m) * rc;
        v.w = __expf(v.w - m) * rc;
        *(float4*)(attn + off) = v;
        t[cc + 0][r] = f2bf(v.x);
        t[cc + 1][r] = f2bf(v.y);
        t[cc + 2][r] = f2bf(v.z);
        t[cc + 3][r] = f2bf(v.w);
    }
    __syncthreads();
    int wr = tid >> 3, wc = (tid & 7) << 3;
#pragma unroll
    for (int p = 0; p < 2; ++p) {
        int c = wr + p * 32;
        uint4 v8 = *(const uint4*)&t[c][wc];
        *(uint4*)(At + (size_t)(s0 + c) * S_SEQ + t0 + wc) = v8;
    }
}

// ---------------- classifier: c = x @ Wc + bc ----------------
__global__ __launch_bounds__(256) void k_classifier(const float* __restrict__ x,
                                                    const float* __restrict__ Wc,
                                                    const float* __restrict__ bc,
                                                    float* __restrict__ outc) {
    __shared__ float red[4][NCLS];
    int row = blockIdx.x, tid = threadIdx.x;
    float4 xv = *(const float4*)(x + (size_t)row * D_DIM + tid * 4);
    const float* w0 = Wc + (size_t)(tid * 4) * NCLS;
    float acc[NCLS];
#pragma unroll
    for (int j = 0; j < NCLS; ++j)
        acc[j] = xv.x * w0[j] + xv.y * w0[NCLS + j] + xv.z * w0[2 * NCLS + j] + xv.w * w0[3 * NCLS + j];
#pragma unroll
    for (int j = 0; j < NCLS; ++j)
#pragma unroll
        for (int o = 32; o; o >>= 1) acc[j] += __shfl_down(acc[j], o);
    int lane = tid & 63, wv = tid >> 6;
    if (lane == 0) {
#pragma unroll
        for (int j = 0; j < NCLS; ++j) red[wv][j] = acc[j];
    }
    __syncthreads();
    if (tid < NCLS) {
        float s = red[0][tid] + red[1][tid] + red[2][tid] + red[3][tid];
        outc[(size_t)row * NCLS + tid] = s + bc[tid];
    }
}

// ============ pipelined bf16 GEMM: C[M,N] = scale*A[M,K]*B[N,K]^T (+bias) ============
// BM=256, BK=32, 512 threads (8 waves), 4 LDS buffers, 3-tiles-ahead prefetch with
// counted vmcnt, LDS XOR swizzle via inverse-swizzled global source, setprio around
// MFMA, bijective XCD block swizzle (bn-fastest). Output: fp32 C (+bias) when Cb
// is null, else bf16 Cb. Optional fused softmax-stat epilogue (pmax/psum).
template<int BN, int WM, int WN>
__global__ __launch_bounds__(512) void k_gemm_big(const unsigned short* __restrict__ A,
                                                  const unsigned short* __restrict__ B,
                                                  float* __restrict__ C,
                                                  unsigned short* __restrict__ Cb,
                                                  int M, int N, int K,
                                                  float scale,
                                                  const float* __restrict__ bias,
                                                  float* __restrict__ pmax,
                                                  float* __restrict__ psum) {
    constexpr int MREP = 256 / WM / 16;
    constexpr int NREP = BN / WN / 16;
    constexpr int PHASES = MREP / 4;
    constexpr int BISS = BN / 128;
    constexpr int TISS = 2 + BISS;
    constexpr int ASLOT = 256 * 32;
    constexpr int BSLOT = BN * 32;
    constexpr int SLOT = ASLOT + BSLOT;
    __shared__ unsigned short lds[4 * SLOT];

    const int tid = threadIdx.x;
    const int lane = tid & 63;
    const int wid = tid >> 6;
    const int wm = wid / WN;
    const int wn = wid % WN;
    const int fm = lane & 15;
    const int g = lane >> 4;

    // bijective XCD swizzle (grid % 8 == 0), bn-fastest decomposition
    const int nbn = N / BN;
    const int nwg = gridDim.x;
    int bid = blockIdx.x;
    int wg = ((nwg & 7) == 0) ? ((bid & 7) * (nwg >> 3) + (bid >> 3)) : bid;
    const int bm = wg / nbn;
    const int bn = wg % nbn;
    const int brow = bm << 8;
    const int bcol = bn * BN;

    const int NT = K >> 5;

    // ----- staging (inverse-swizzled global source, linear LDS dest) -----
    const int arow = tid >> 2;
    const int scb = ((tid & 3) << 4) ^ ((arow & 6) << 3);
    const unsigned short* gA = A + (size_t)(brow + arow) * K + (scb >> 1);
    const unsigned short* gB = B + (size_t)(bcol + arow) * K + (scb >> 1);
    unsigned short* lA = lds + tid * 8;
    unsigned short* lB = lds + ASLOT + tid * 8;
    const size_t rows128 = (size_t)128 * K;

    auto stageA = [&](int kt, int slot) {
        const unsigned short* s = gA + ((size_t)kt << 5);
        unsigned short* d = lA + slot * SLOT;
        GLL(s, d);
        GLL(s + rows128, d + 4096);
    };
    auto stageB = [&](int kt, int slot) {
        const unsigned short* s = gB + ((size_t)kt << 5);
        unsigned short* d = lB + slot * SLOT;
#pragma unroll
        for (int h = 0; h < BISS; ++h)
            GLL(s + (size_t)h * rows128, d + h * 4096);
    };

    // ----- fragment read bases (swizzled) -----
    const int cbf = (((g << 4) ^ ((fm & 6) << 3)) >> 1);
    const unsigned short* fA = lds + (wm * (256 / WM) + fm) * 32 + cbf;
    const unsigned short* fB = lds + ASLOT + (wn * (BN / WN) + fm) * 32 + cbf;

    f32x4 acc[MREP][NREP] = {};

    stageA(0, 0); stageB(0, 0);
    stageA(1, 1); stageB(1, 1);
    stageA(2, 2); stageB(2, 2);
    asm volatile("s_waitcnt vmcnt(%0)" :: "n"(2 * TISS) : "memory");
    __builtin_amdgcn_s_barrier();

    for (int t = 0; t < NT; ++t) {
        const int slot = t & 3;
        const unsigned short* sA = fA + slot * SLOT;
        const unsigned short* sB = fB + slot * SLOT;
        const int pslot = (t + 3) & 3;
        const bool pf = (t + 3) < NT;

        bf16x8 bfr[NREP];
        bf16x8 afr[4];
#pragma unroll
        for (int i = 0; i < 4; ++i) afr[i] = *(const bf16x8*)(sA + i * 512);
#pragma unroll
        for (int j = 0; j < NREP; ++j) bfr[j] = *(const bf16x8*)(sB + j * 512);
        if (pf) {
            stageA(t + 3, pslot);
            if (PHASES == 1) stageB(t + 3, pslot);
        }
        __builtin_amdgcn_s_barrier();
        asm volatile("s_waitcnt lgkmcnt(0)" ::: "memory");
        __builtin_amdgcn_s_setprio(1);
#pragma unroll
        for (int i = 0; i < 4; ++i)
#pragma unroll
            for (int j = 0; j < NREP; ++j)
                acc[i][j] = __builtin_amdgcn_mfma_f32_16x16x32_bf16(afr[i], bfr[j], acc[i][j], 0, 0, 0);
        __builtin_amdgcn_s_setprio(0);
        __builtin_amdgcn_s_barrier();

        if (PHASES == 2) {
#pragma unroll
            for (int i = 0; i < 4; ++i) afr[i] = *(const bf16x8*)(sA + (i + 4) * 512);
            if (pf) stageB(t + 3, pslot);
            __builtin_amdgcn_s_barrier();
            asm volatile("s_waitcnt lgkmcnt(0)" ::: "memory");
            __builtin_amdgcn_s_setprio(1);
#pragma unroll
            for (int i = 0; i < 4; ++i)
#pragma unroll
                for (int j = 0; j < NREP; ++j)
                    acc[(i + 4) % MREP][j] = __builtin_amdgcn_mfma_f32_16x16x32_bf16(afr[i], bfr[j], acc[(i + 4) % MREP][j], 0, 0, 0);
            __builtin_amdgcn_s_setprio(0);
        }

        if (t + 1 < NT) {
            if (t + 3 < NT)
                asm volatile("s_waitcnt vmcnt(%0)" :: "n"(2 * TISS) : "memory");
            else if (t + 2 < NT)
                asm volatile("s_waitcnt vmcnt(%0)" :: "n"(TISS) : "memory");
            else
                asm volatile("s_waitcnt vmcnt(0)" ::: "memory");
        }
        __builtin_amdgcn_s_barrier();
    }

    // ---- fused softmax-stat epilogue (per-row max & sum-exp over 64 cols) ----
    if (psum) {
        const int nblk = N >> 6;
        const int cblk = (bcol >> 6) + wn;
#pragma unroll
        for (int i = 0; i < MREP; ++i) {
#pragma unroll
            for (int r = 0; r < 4; ++r) {
                float v0 = acc[i][0][r] * scale, v1 = acc[i][1][r] * scale;
                float v2 = acc[i][2][r] * scale, v3 = acc[i][3][r] * scale;
                float mv = fmaxf(fmaxf(v0, v1), fmaxf(v2, v3));
#pragma unroll
                for (int mk = 1; mk < 16; mk <<= 1) mv = fmaxf(mv, __shfl_xor(mv, mk));
                float sv = __expf(v0 - mv) + __expf(v1 - mv) + __expf(v2 - mv) + __expf(v3 - mv);
#pragma unroll
                for (int mk = 1; mk < 16; mk <<= 1) sv += __shfl_xor(sv, mk);
                if (fm == 0) {
                    int row = brow + wm * (256 / WM) + i * 16 + (g << 2) + r;
                    pmax[(size_t)row * nblk + cblk] = mv;
                    psum[(size_t)row * nblk + cblk] = sv;
                }
            }
        }
    }

    // ---- store ----
    const int r0 = g << 2;
    if (Cb) {
#pragma unroll
        for (int i = 0; i < MREP; ++i) {
#pragma unroll
            for (int j = 0; j < NREP; ++j) {
                int col = bcol + wn * (BN / WN) + j * 16 + fm;
#pragma unroll
                for (int r = 0; r < 4; ++r) {
                    int row = brow + wm * (256 / WM) + i * 16 + r0 + r;
                    Cb[(size_t)row * N + col] = f2bf(acc[i][j][r] * scale);
                }
            }
        }
    } else {
#pragma unroll
        for (int i = 0; i < MREP; ++i) {
#pragma unroll
            for (int j = 0; j < NREP; ++j) {
                int col = bcol + wn * (BN / WN) + j * 16 + fm;
                float badd = bias ? bias[col] : 0.0f;
#pragma unroll
                for (int r = 0; r < 4; ++r) {
                    int row = brow + wm * (256 / WM) + i * 16 + r0 + r;
                    C[(size_t)row * N + col] = acc[i][j][r] * scale + badd;
                }
            }
        }
    }
}

extern "C" void kernel_launch(void* const* d_in, const int* in_sizes, int n_in,
                              void* d_out, int out_size, void* d_ws, size_t ws_size,
                              hipStream_t stream) {
    const float* x     = (const float*)d_in[0];
    const float* Wq    = (const float*)d_in[1];
    const float* bq    = (const float*)d_in[2];
    const float* gq    = (const float*)d_in[3];
    const float* betaq = (const float*)d_in[4];
    const float* Wk    = (const float*)d_in[5];
    const float* bk    = (const float*)d_in[6];
    const float* gk    = (const float*)d_in[7];
    const float* betak = (const float*)d_in[8];
    const float* Wv    = (const float*)d_in[9];
    const float* bv    = (const float*)d_in[10];
    const float* gv    = (const float*)d_in[11];
    const float* betav = (const float*)d_in[12];
    const float* Wo    = (const float*)d_in[13];
    const float* bo    = (const float*)d_in[14];
    const float* Wc    = (const float*)d_in[15];
    const float* bc    = (const float*)d_in[16];

    float* out_o    = (float*)d_out;
    float* out_c    = out_o + (size_t)S_SEQ * D_DIM;
    float* out_attn = out_c + (size_t)S_SEQ * NCLS;

    char* cur = (char*)d_ws;
    auto alloc = [&](size_t bytes) {
        char* p = cur;
        cur += (bytes + 255) & ~(size_t)255;
        return p;
    };
    const size_t SD2 = (size_t)S_SEQ * D_DIM * 2;
    const size_t DD2 = (size_t)D_DIM * D_DIM * 2;
    unsigned short* xb   = (unsigned short*)alloc(SD2);
    unsigned short* wqkv = (unsigned short*)alloc(3 * DD2);
    unsigned short* wto  = (unsigned short*)alloc(DD2);
    unsigned short* qb   = (unsigned short*)alloc(SD2);
    unsigned short* kb   = (unsigned short*)alloc(SD2);
    unsigned short* vb   = (unsigned short*)alloc(SD2);
    unsigned short* Vt   = (unsigned short*)alloc(SD2);
    unsigned short* valb = (unsigned short*)alloc(SD2);
    float* rmax   = (float*)alloc((size_t)S_SEQ * 4);
    float* rrecip = (float*)alloc((size_t)S_SEQ * 4);
    unsigned short* At = (unsigned short*)alloc((size_t)S_SEQ * S_SEQ * 2);
    unsigned short* Lb = (unsigned short*)alloc((size_t)S_SEQ * S_SEQ * 2);
    const bool use_lb = (size_t)(cur - (char*)d_ws) <= ws_size;

    // overlays: pmax/psum (8192 x 128 fp32 each) over xb (dead after QKV GEMM)
    float* pmax = (float*)xb;
    float* psum = pmax + (size_t)S_SEQ * 128;

    const int n4_xd = S_SEQ * D_DIM / 4;

    // x -> bf16
    k_f32_to_bf16<<<n4_xd / 256, 256, 0, stream>>>(x, xb, n4_xd);
    // weight transposes: fp32 [K][N] -> bf16 [N][K]; q/k/v concatenated along N
    k_transpose_f32_bf16<<<dim3(16, 16), 256, 0, stream>>>(Wq, wqkv, D_DIM, D_DIM);
    k_transpose_f32_bf16<<<dim3(16, 16), 256, 0, stream>>>(Wk, wqkv + (size_t)D_DIM * D_DIM, D_DIM, D_DIM);
    k_transpose_f32_bf16<<<dim3(16, 16), 256, 0, stream>>>(Wv, wqkv + (size_t)2 * D_DIM * D_DIM, D_DIM, D_DIM);
    k_transpose_f32_bf16<<<dim3(16, 16), 256, 0, stream>>>(Wo, wto, D_DIM, D_DIM);
    // classifier (independent)
    k_classifier<<<S_SEQ, 256, 0, stream>>>(x, Wc, bc, out_c);

    // fused QKV GEMM: [8192][3072] fp32 into out_attn scratch
    float* qkv = out_attn;
    k_gemm_big<128, 4, 2><<<(S_SEQ / 256) * (3 * D_DIM / 128), 512, 0, stream>>>(
        xb, wqkv, qkv, nullptr, S_SEQ, 3 * D_DIM, D_DIM, 1.0f, nullptr, nullptr, nullptr);
    // per-chain LayerNorm -> bf16
    k_ln_bf16<<<S_SEQ, 256, 0, stream>>>(qkv,              3 * D_DIM, bq, gq, betaq, qb);
    k_ln_bf16<<<S_SEQ, 256, 0, stream>>>(qkv + D_DIM,      3 * D_DIM, bk, gk, betak, kb);
    k_ln_bf16<<<S_SEQ, 256, 0, stream>>>(qkv + 2 * D_DIM,  3 * D_DIM, bv, gv, betav, vb);

    // V^T for the A^T V GEMM
    k_transpose_bf16<<<dim3(S_SEQ / 64, D_DIM / 64), 256, 0, stream>>>(vb, Vt, S_SEQ, D_DIM);

    // logits = q k^T / 32, fused per-tile softmax stats.
    // Preferred: bf16 logits to Lb (halves write + later read). Fallback: fp32 to out_attn.
    if (use_lb) {
        k_gemm_big<256, 2, 4><<<(S_SEQ / 256) * (S_SEQ / 256), 512, 0, stream>>>(
            qb, kb, nullptr, Lb, S_SEQ, S_SEQ, D_DIM, 0.03125f, nullptr, pmax, psum);
    } else {
        k_gemm_big<256, 2, 4><<<(S_SEQ / 256) * (S_SEQ / 256), 512, 0, stream>>>(
            qb, kb, out_attn, nullptr, S_SEQ, S_SEQ, D_DIM, 0.03125f, nullptr, pmax, psum);
    }

    // combine stats, then normalize -> fp32 attention output + bf16 At
    k_stats_reduce<<<S_SEQ / 4, 256, 0, stream>>>(pmax, psum, rmax, rrecip, S_SEQ / 64);
    if (use_lb) {
        k_norm_transpose<1><<<dim3(S_SEQ / 64, S_SEQ / 64), 256, 0, stream>>>(
            Lb, nullptr, out_attn, rmax, rrecip, At);
    } else {
        k_norm_transpose<0><<<dim3(S_SEQ / 64, S_SEQ / 64), 256, 0, stream>>>(
            nullptr, out_attn, out_attn, rmax, rrecip, At);
    }

    // values = A^T V -> bf16 valb directly
    k_gemm_big<128, 4, 2><<<(S_SEQ / 256) * (D_DIM / 128), 512, 0, stream>>>(
        At, Vt, nullptr, valb, S_SEQ, D_DIM, S_SEQ, 1.0f, nullptr, nullptr, nullptr);

    // o = values @ Wo + bo
    k_gemm_big<128, 4, 2><<<(S_SEQ / 256) * (D_DIM / 128), 512, 0, stream>>>(
        valb, wto, out_o, nullptr, S_SEQ, D_DIM, D_DIM, 1.0f, bo, nullptr, nullptr);
}